// Round 10
// baseline (327.961 us; speedup 1.0000x reference)
//
#include <hip/hip_runtime.h>
#include <hip/hip_bf16.h>
#include <stdint.h>

#define NB    32
#define CIN   128
#define HIN   56
#define HW    (HIN*HIN)     // 3136
#define OCH   256
#define OHW   54
#define SPB   (OHW*OHW)     // 2916
#define KSZ   (CIN*9)       // 1152 = GEMM K
#define BM    256           // oc rows per block (= OCH)
#define BN    384           // flattened (n,sp) cols; 93312/384 = 243 exact
#define BK    64
#define NKS   (KSZ/BK)      // 18 K-tiles
#define TOTC  (NB*SPB)      // 93312
#define NT    243           // single ~95% grid round
#define BGRAN (BN*8)        // 3072 B-granules (16B) per buffer = 48KB

typedef __attribute__((ext_vector_type(8))) short bf16x8;
typedef __attribute__((ext_vector_type(4))) float f32x4;

typedef __attribute__((address_space(1))) const uint32_t g_u32;
typedef __attribute__((address_space(3))) uint32_t l_u32;
static __device__ __forceinline__ void gl_lds16(const void* g, void* l) {
    __builtin_amdgcn_global_load_lds((g_u32*)g, (l_u32*)l, 16, 0, 0);
}

// ---- pre-pass 1: x NCHW f32 -> NHWC bf16 ----
__global__ void xpose_cast(const float* __restrict__ x, __hip_bfloat16* __restrict__ xt) {
    __shared__ float tile[32][33];
    const int hw0 = blockIdx.x * 32;
    const int c0  = blockIdx.y * 32;
    const int n   = blockIdx.z;
    const int tx = threadIdx.x, ty = threadIdx.y;
    const float* xp = x + ((size_t)n*CIN + c0)*HW + hw0;
    #pragma unroll
    for (int i = ty; i < 32; i += 8)
        tile[i][tx] = xp[(size_t)i*HW + tx];
    __syncthreads();
    const int t = ty*32 + tx;
    const int hwl = t >> 3, q = t & 7;
    ushort4 v;
    v.x = __bfloat16_as_ushort(__float2bfloat16(tile[q*4+0][hwl]));
    v.y = __bfloat16_as_ushort(__float2bfloat16(tile[q*4+1][hwl]));
    v.z = __bfloat16_as_ushort(__float2bfloat16(tile[q*4+2][hwl]));
    v.w = __bfloat16_as_ushort(__float2bfloat16(tile[q*4+3][hwl]));
    __hip_bfloat16* op = xt + ((size_t)n*HW + hw0 + hwl)*CIN + c0 + q*4;
    *(ushort4*)op = v;
}

// ---- pre-pass 2: weight OIHW f32 -> [oc][(kh*3+kw)*128+ic] bf16 ----
__global__ void wcast(const float* __restrict__ w, __hip_bfloat16* __restrict__ wt) {
    int tid = blockIdx.x*256 + threadIdx.x;
    if (tid >= OCH*KSZ) return;
    int oc = tid / KSZ, r = tid % KSZ;
    int pos = r >> 7, ic = r & 127;
    wt[tid] = __float2bfloat16(w[((size_t)(oc*CIN + ic))*9 + pos]);
}

// ---- main: implicit-GEMM bf16 MFMA conv, A-in-registers / B-only-LDS ----
// grid (243), block 512 = 8 waves (2M x 4N), per-wave 128x96 (acc 8x6).
// A (weights): global->VGPR per tile (L1/L2-resident), prefetch distance 1.
// B: LDS double buffer 2x48KB via gl_lds, 8-slot XOR swizzle (round-9-verified).
// One barrier/tile; counted vmcnt(14)/(8) keeps loads in flight across it.
__global__ __launch_bounds__(512, 2)
void conv_mfma(const __hip_bfloat16* __restrict__ xt,
               const __hip_bfloat16* __restrict__ wt,
               const float* __restrict__ bias,
               float* __restrict__ out) {
    __shared__ uint4 smem[2*BGRAN];   // 98304 B

    const int t = threadIdx.x;
    // bijective XCD swizzle: nwg=243 = 8*30+3 -> q=30, r=3
    const int orig = blockIdx.x;
    const int xcd = orig & 7;
    const int tile = (xcd < 3 ? xcd*31 : 3*31 + (xcd-3)*30) + (orig >> 3);

    const int lane = t & 63, wid = t >> 6;
    const int wm = wid >> 2, wn = wid & 3;     // per-wave 128 rows x 96 cols
    const int lr = lane & 15, lq = lane >> 4;

    // A per-lane base: row = wm*128 + mi*16 + lr, k-chunk lq
    const __hip_bfloat16* abase = wt + (size_t)(wm*128 + lr)*KSZ + lq*8;

    // B staging sources: 3072 granules / 512 thr = 6 gl_lds; [col][slot j],
    // slot j holds k-chunk j ^ (col&7) (2-way banks = free)
    const __hip_bfloat16* bsrc[6];
    #pragma unroll
    for (int i = 0; i < 6; ++i) {
        int q = i*512 + t;
        int col = q >> 3, j = q & 7;
        int ls = j ^ (col & 7);
        int colg = tile*BN + col;              // exact tiling: < TOTC always
        int n = colg / SPB, rem = colg - n*SPB;
        int oh = rem / OHW, ow = rem - oh*OHW;
        bsrc[i] = xt + ((size_t)(n*HIN + oh)*HIN + ow)*CIN + ls*8;
    }

    auto stageB = [&](int ks) {      // 6 gl_lds -> buf[ks&1]
        uint4* dst = smem + (ks & 1)*BGRAN;
        const int pos = ks >> 1;
        const int kh = pos / 3, kw = pos - kh*3;
        const int boff = (kh*HIN + kw)*CIN + (ks & 1)*64;
        #pragma unroll
        for (int i = 0; i < 6; ++i) gl_lds16(bsrc[i] + boff, dst + i*512 + t);
    };

    // B read offsets (granule units), kk=0; kk=1 toggles ^4
    int bo[6];
    #pragma unroll
    for (int ni = 0; ni < 6; ++ni) {
        int c = wn*96 + ni*16 + lr;
        bo[ni] = c*8 + (lq ^ (c & 7));
    }

    f32x4 acc[8][6];
    #pragma unroll
    for (int i = 0; i < 8; ++i)
        #pragma unroll
        for (int j = 0; j < 6; ++j)
            acc[i][j] = (f32x4){0.f, 0.f, 0.f, 0.f};

    #define MFMA_BF16 __builtin_amdgcn_mfma_f32_16x16x32_bf16
    #define LDA8(ARR, KOFF) \
        _Pragma("unroll") \
        for (int mi = 0; mi < 8; ++mi) \
            ARR[mi] = *(const bf16x8*)(abase + (size_t)mi*16*KSZ + (KOFF));
    #define MFMA48(AARR, BARR) \
        __builtin_amdgcn_s_setprio(1); \
        _Pragma("unroll") \
        for (int mi = 0; mi < 8; ++mi) \
            _Pragma("unroll") \
            for (int ni = 0; ni < 6; ++ni) \
                acc[mi][ni] = MFMA_BF16(AARR[mi], BARR[ni], acc[mi][ni], 0, 0, 0); \
        __builtin_amdgcn_s_setprio(0);

    bf16x8 a0[8], a1[8];

    // prologue: A(t0) both halves + B(t0); full certify
    LDA8(a0, 0)
    LDA8(a1, 32)
    stageB(0);
    asm volatile("s_waitcnt vmcnt(0)" ::: "memory");
    __builtin_amdgcn_s_barrier();
    __builtin_amdgcn_sched_barrier(0);

    for (int ks = 0; ks < NKS; ++ks) {
        const uint4* Bb = smem + (ks & 1)*BGRAN;
        const bool pf = (ks + 1 < NKS);
        bf16x8 b0[6], b1[6];
        #pragma unroll
        for (int ni = 0; ni < 6; ++ni) b0[ni] = *(const bf16x8*)&Bb[bo[ni]];
        #pragma unroll
        for (int ni = 0; ni < 6; ++ni) b1[ni] = *(const bf16x8*)&Bb[bo[ni] ^ 4];

        asm volatile("s_waitcnt lgkmcnt(6)" ::: "memory");   // b0 ready
        __builtin_amdgcn_sched_barrier(0);
        MFMA48(a0, b0)

        // prefetch next tile: A kk0 (regs) + B stage (gl_lds)
        if (pf) { LDA8(a0, (ks+1)*BK) }
        if (pf) stageB(ks + 1);

        asm volatile("s_waitcnt lgkmcnt(0)" ::: "memory");   // b1 ready
        // retire prev-tile A-kk1 (oldest 8); leave this tile's A0'(8)+B(6) flying
        if (pf) asm volatile("s_waitcnt vmcnt(14)" ::: "memory");
        else    asm volatile("s_waitcnt vmcnt(0)" ::: "memory");
        __builtin_amdgcn_sched_barrier(0);
        MFMA48(a1, b1)

        if (pf) { LDA8(a1, (ks+1)*BK + 32) }

        // boundary: retire A0'+B (oldest 14), leave A1'(8) flying; publish buffer
        if (pf) {
            asm volatile("s_waitcnt vmcnt(8)" ::: "memory");
            __builtin_amdgcn_s_barrier();
            __builtin_amdgcn_sched_barrier(0);
        }
    }

    __syncthreads();

    // --- epilogue: LDS restage [64][196] (2-way free), 2 col-halves, float4 stores ---
    float (*eps)[196] = (float (*)[196])smem;
    const int cl4 = (t % 48) * 4;                 // 0..188
    const int rsub = t / 48;                      // 0..7 for t<384
    #pragma unroll
    for (int h = 0; h < 4; ++h) {
        #pragma unroll
        for (int half = 0; half < 2; ++half) {
            if (wm == (h >> 1) && (wn >> 1) == half) {
                const int mib = (h & 1) * 4;
                #pragma unroll
                for (int ii = 0; ii < 4; ++ii) {
                    int rl = ii*16 + lq*4;
                    #pragma unroll
                    for (int ni = 0; ni < 6; ++ni) {
                        int cl = (wn & 1)*96 + ni*16 + lr;
                        #pragma unroll
                        for (int r = 0; r < 4; ++r)
                            eps[rl + r][cl] = acc[mib + ii][ni][r];
                    }
                }
            }
            __syncthreads();
            if (t < 384) {
                const int colg = tile*BN + half*192 + cl4;
                const int nn = colg / SPB;
                const int sp = colg - nn*SPB;     // SPB%4==0 -> no straddle
                #pragma unroll
                for (int pass = 0; pass < 8; ++pass) {
                    int rl = pass*8 + rsub;
                    int rg = h*64 + rl;
                    f32x4 v = *(f32x4*)&eps[rl][cl4];
                    v = v + bias[rg];
                    *(f32x4*)&out[((size_t)nn*OCH + rg)*SPB + sp] = v;
                }
            }
            __syncthreads();
        }
    }
}

// ---- fallback: direct fp32 conv ----
__global__ void conv_naive(const float* __restrict__ x, const float* __restrict__ w,
                           const float* __restrict__ bias, float* __restrict__ out) {
    size_t tid = (size_t)blockIdx.x*256 + threadIdx.x;
    const size_t total = (size_t)NB*OCH*SPB;
    if (tid >= total) return;
    int col = (int)(tid % SPB);
    int oc  = (int)((tid / SPB) % OCH);
    int n   = (int)(tid / ((size_t)SPB*OCH));
    int oh = col / OHW, ow = col % OHW;
    float s = bias[oc];
    for (int ic = 0; ic < CIN; ++ic)
        #pragma unroll
        for (int kh = 0; kh < 3; ++kh)
            #pragma unroll
            for (int kw = 0; kw < 3; ++kw)
                s += x[((size_t)(n*CIN+ic)*HIN + oh+kh)*HIN + ow+kw]
                   * w[((size_t)(oc*CIN+ic)*3 + kh)*3 + kw];
    out[tid] = s;
}

extern "C" void kernel_launch(void* const* d_in, const int* in_sizes, int n_in,
                              void* d_out, int out_size, void* d_ws, size_t ws_size,
                              hipStream_t stream) {
    const float* x    = (const float*)d_in[0];
    const float* w    = (const float*)d_in[1];
    const float* bias = (const float*)d_in[2];
    float* out = (float*)d_out;

    const size_t xt_bytes = (size_t)NB*HW*CIN*sizeof(__hip_bfloat16);
    const size_t wt_bytes = (size_t)OCH*KSZ*sizeof(__hip_bfloat16);

    if (ws_size >= xt_bytes + wt_bytes) {
        __hip_bfloat16* xt  = (__hip_bfloat16*)d_ws;
        __hip_bfloat16* wtp = (__hip_bfloat16*)((char*)d_ws + xt_bytes);
        hipLaunchKernelGGL(xpose_cast, dim3(HW/32, CIN/32, NB), dim3(32, 8), 0, stream, x, xt);
        hipLaunchKernelGGL(wcast, dim3((OCH*KSZ + 255)/256), dim3(256), 0, stream, w, wtp);
        hipLaunchKernelGGL(conv_mfma, dim3(NT), dim3(512), 0, stream, xt, wtp, bias, out);
    } else {
        size_t total = (size_t)NB*OCH*SPB;
        hipLaunchKernelGGL(conv_naive, dim3((unsigned)((total + 255)/256)), dim3(256), 0, stream,
                           x, w, bias, out);
    }
}

// Round 11
// 84.137 us; speedup vs baseline: 3.8979x; 3.8979x over previous
//
#include <hip/hip_runtime.h>
#include <hip/hip_bf16.h>
#include <stdint.h>

#define NB    32
#define CIN   128
#define HIN   56
#define HW    (HIN*HIN)     // 3136
#define OCH   256
#define OHW   54
#define SPB   (OHW*OHW)     // 2916
#define KSZ   (CIN*9)       // 1152 = GEMM K
#define BM    256           // oc rows per block (= OCH)
#define BN    128           // flattened (n,sp) cols; 93312/128 = 729 exact
#define BK    32
#define NKS   (KSZ/BK)      // 36 K-tiles
#define TOTC  (NB*SPB)      // 93312
#define NT    729
#define GRAN  1536          // (BM+BN)*4 granules (16B) per buffer = 24KB

typedef __attribute__((ext_vector_type(8))) short bf16x8;
typedef __attribute__((ext_vector_type(4))) float f32x4;

typedef __attribute__((address_space(1))) const uint32_t g_u32;
typedef __attribute__((address_space(3))) uint32_t l_u32;
static __device__ __forceinline__ void gl_lds16(const void* g, void* l) {
    __builtin_amdgcn_global_load_lds((g_u32*)g, (l_u32*)l, 16, 0, 0);
}

// ---- pre-pass 1: x NCHW f32 -> NHWC bf16 ----
__global__ void xpose_cast(const float* __restrict__ x, __hip_bfloat16* __restrict__ xt) {
    __shared__ float tile[32][33];
    const int hw0 = blockIdx.x * 32;
    const int c0  = blockIdx.y * 32;
    const int n   = blockIdx.z;
    const int tx = threadIdx.x, ty = threadIdx.y;
    const float* xp = x + ((size_t)n*CIN + c0)*HW + hw0;
    #pragma unroll
    for (int i = ty; i < 32; i += 8)
        tile[i][tx] = xp[(size_t)i*HW + tx];
    __syncthreads();
    const int t = ty*32 + tx;
    const int hwl = t >> 3, q = t & 7;
    ushort4 v;
    v.x = __bfloat16_as_ushort(__float2bfloat16(tile[q*4+0][hwl]));
    v.y = __bfloat16_as_ushort(__float2bfloat16(tile[q*4+1][hwl]));
    v.z = __bfloat16_as_ushort(__float2bfloat16(tile[q*4+2][hwl]));
    v.w = __bfloat16_as_ushort(__float2bfloat16(tile[q*4+3][hwl]));
    __hip_bfloat16* op = xt + ((size_t)n*HW + hw0 + hwl)*CIN + c0 + q*4;
    *(ushort4*)op = v;
}

// ---- pre-pass 2: weight OIHW f32 -> [oc][(kh*3+kw)*128+ic] bf16 ----
__global__ void wcast(const float* __restrict__ w, __hip_bfloat16* __restrict__ wt) {
    int tid = blockIdx.x*256 + threadIdx.x;
    if (tid >= OCH*KSZ) return;
    int oc = tid / KSZ, r = tid % KSZ;
    int pos = r >> 7, ic = r & 127;
    wt[tid] = __float2bfloat16(w[((size_t)(oc*CIN + ic))*9 + pos]);
}

// ---- main: implicit-GEMM bf16 MFMA conv ----
// grid (729), block 256 = 4 waves (2M x 2N), per-wave 128x64 (acc 8x4).
// BK=32, TRIPLE buffer (3 x 24KB = 72KB -> 2 blocks/CU for cross-block overlap),
// one barrier + counted vmcnt(6) per K-tile, free-running waves, prefetch dist 2.
// LDS layout per buffer: [A rows 0..255 | B cols 0..127] x 4 slots/row;
// slot j holds logical k-chunk j ^ ((row>>1)&3)  (uniform 8 reads/bank-pos).
__global__ __launch_bounds__(256, 2)
void conv_mfma(const __hip_bfloat16* __restrict__ xt,
               const __hip_bfloat16* __restrict__ wt,
               const float* __restrict__ bias,
               float* __restrict__ out) {
    __shared__ uint4 smem[3*GRAN];   // 73728 B

    const int t = threadIdx.x;
    // bijective XCD swizzle: nwg=729 = 8*91+1 -> q=91, r=1
    const int orig = blockIdx.x;
    const int xcd = orig & 7;
    const int tile = (xcd < 1 ? xcd*92 : 92 + (xcd-1)*91) + (orig >> 3);

    const int lane = t & 63, wid = t >> 6;
    const int wm = wid >> 1, wn = wid & 1;     // per-wave 128 rows x 64 cols
    const int lr = lane & 15, lq = lane >> 4;

    // staging sources: A 1024 granules (4/thread), B 512 granules (2/thread)
    const __hip_bfloat16* asrc[4];
    #pragma unroll
    for (int i = 0; i < 4; ++i) {
        int q = i*256 + t;
        int row = q >> 2, j = q & 3;
        int ls = j ^ ((row >> 1) & 3);
        asrc[i] = wt + (size_t)row*KSZ + ls*8;
    }
    const __hip_bfloat16* bsrc[2];
    #pragma unroll
    for (int i = 0; i < 2; ++i) {
        int q = i*256 + t;
        int col = q >> 2, j = q & 3;
        int ls = j ^ ((col >> 1) & 3);
        int colg = tile*BN + col;              // exact tiling: < TOTC always
        int n = colg / SPB, rem = colg - n*SPB;
        int oh = rem / OHW, ow = rem - oh*OHW;
        bsrc[i] = xt + ((size_t)(n*HIN + oh)*HIN + ow)*CIN + ls*8;
    }

    auto issueT = [&](uint4* dst, int ks) {    // 6 gl_lds: tile ks -> dst buffer
        const int aoff = ks*BK;
        const int pos = ks >> 2;
        const int kh = pos / 3, kw = pos - kh*3;
        const int boff = (kh*HIN + kw)*CIN + (ks & 3)*32;
        #pragma unroll
        for (int i = 0; i < 4; ++i) gl_lds16(asrc[i] + aoff, dst + i*256 + t);
        #pragma unroll
        for (int i = 0; i < 2; ++i) gl_lds16(bsrc[i] + boff, dst + 1024 + i*256 + t);
    };

    // per-lane read offsets (granule units)
    int ao[8], bo[4];
    #pragma unroll
    for (int mi = 0; mi < 8; ++mi) {
        int ra = wm*128 + mi*16 + lr;
        ao[mi] = ra*4 + (lq ^ ((ra >> 1) & 3));
    }
    #pragma unroll
    for (int ni = 0; ni < 4; ++ni) {
        int cb = wn*64 + ni*16 + lr;
        bo[ni] = 1024 + cb*4 + (lq ^ ((cb >> 1) & 3));
    }

    f32x4 acc[8][4];
    #pragma unroll
    for (int i = 0; i < 8; ++i)
        #pragma unroll
        for (int j = 0; j < 4; ++j)
            acc[i][j] = (f32x4){0.f, 0.f, 0.f, 0.f};

    #define MFMA_BF16 __builtin_amdgcn_mfma_f32_16x16x32_bf16

    uint4 *pR = smem, *pN = smem + GRAN, *pS = smem + 2*GRAN;

    // prologue: tiles 0,1 in flight; certify 0 (oldest 6), leave 1 flying
    issueT(pR, 0); issueT(pN, 1);
    asm volatile("s_waitcnt vmcnt(6)" ::: "memory");
    __builtin_amdgcn_s_barrier();
    __builtin_amdgcn_sched_barrier(0);

    for (int ks = 0; ks < NKS; ++ks) {
        bf16x8 aa[4], ab[4], bb[4];
        #pragma unroll
        for (int mi = 0; mi < 4; ++mi) aa[mi] = *(bf16x8*)&pR[ao[mi]];
        #pragma unroll
        for (int ni = 0; ni < 4; ++ni) bb[ni] = *(bf16x8*)&pR[bo[ni]];
        if (ks + 2 < NKS) issueT(pS, ks + 2);
        #pragma unroll
        for (int mi = 0; mi < 4; ++mi) ab[mi] = *(bf16x8*)&pR[ao[4 + mi]];

        asm volatile("s_waitcnt lgkmcnt(4)" ::: "memory");   // aa,bb ready
        __builtin_amdgcn_sched_barrier(0);
        __builtin_amdgcn_s_setprio(1);
        #pragma unroll
        for (int mi = 0; mi < 4; ++mi)
            #pragma unroll
            for (int ni = 0; ni < 4; ++ni)
                acc[mi][ni] = MFMA_BF16(aa[mi], bb[ni], acc[mi][ni], 0, 0, 0);
        __builtin_amdgcn_s_setprio(0);

        asm volatile("s_waitcnt lgkmcnt(0)" ::: "memory");   // ab ready
        __builtin_amdgcn_sched_barrier(0);
        __builtin_amdgcn_s_setprio(1);
        #pragma unroll
        for (int mi = 0; mi < 4; ++mi)
            #pragma unroll
            for (int ni = 0; ni < 4; ++ni)
                acc[4+mi][ni] = MFMA_BF16(ab[mi], bb[ni], acc[4+mi][ni], 0, 0, 0);
        __builtin_amdgcn_s_setprio(0);

        // boundary: certify buf for tile ks+1; leave tile ks+2's 6 loads flying
        if (ks + 1 < NKS) {
            if (ks + 2 < NKS) asm volatile("s_waitcnt vmcnt(6)" ::: "memory");
            else              asm volatile("s_waitcnt vmcnt(0)" ::: "memory");
            __builtin_amdgcn_s_barrier();
            __builtin_amdgcn_sched_barrier(0);
        }
        uint4* tmp = pR; pR = pN; pN = pS; pS = tmp;
    }

    __syncthreads();

    // --- epilogue: LDS restage [64][132] (2-way free), coalesced float4 stores ---
    float (*eps)[132] = (float (*)[132])smem;
    const int cl4 = (t & 31) * 4;                 // 0..124
    const int rsub = t >> 5;                      // 0..7
    const int colg = tile*BN + cl4;
    const int nn = colg / SPB;
    const int sp = colg - nn*SPB;                 // SPB%4==0 -> no straddle
    #pragma unroll
    for (int h = 0; h < 4; ++h) {
        if (wm == (h >> 1)) {
            const int mib = (h & 1) * 4;
            #pragma unroll
            for (int ii = 0; ii < 4; ++ii) {
                int rl = ii*16 + lq*4;
                #pragma unroll
                for (int ni = 0; ni < 4; ++ni) {
                    int cl = wn*64 + ni*16 + lr;
                    #pragma unroll
                    for (int r = 0; r < 4; ++r)
                        eps[rl + r][cl] = acc[mib + ii][ni][r];
                }
            }
        }
        __syncthreads();
        {
            #pragma unroll
            for (int pass = 0; pass < 8; ++pass) {
                int rl = pass*8 + rsub;
                int rg = h*64 + rl;
                f32x4 v = *(f32x4*)&eps[rl][cl4];
                v = v + bias[rg];
                *(f32x4*)&out[((size_t)nn*OCH + rg)*SPB + sp] = v;
            }
        }
        __syncthreads();
    }
}

// ---- fallback: direct fp32 conv ----
__global__ void conv_naive(const float* __restrict__ x, const float* __restrict__ w,
                           const float* __restrict__ bias, float* __restrict__ out) {
    size_t tid = (size_t)blockIdx.x*256 + threadIdx.x;
    const size_t total = (size_t)NB*OCH*SPB;
    if (tid >= total) return;
    int col = (int)(tid % SPB);
    int oc  = (int)((tid / SPB) % OCH);
    int n   = (int)(tid / ((size_t)SPB*OCH));
    int oh = col / OHW, ow = col % OHW;
    float s = bias[oc];
    for (int ic = 0; ic < CIN; ++ic)
        #pragma unroll
        for (int kh = 0; kh < 3; ++kh)
            #pragma unroll
            for (int kw = 0; kw < 3; ++kw)
                s += x[((size_t)(n*CIN+ic)*HIN + oh+kh)*HIN + ow+kw]
                   * w[((size_t)(oc*CIN+ic)*3 + kh)*3 + kw];
    out[tid] = s;
}

extern "C" void kernel_launch(void* const* d_in, const int* in_sizes, int n_in,
                              void* d_out, int out_size, void* d_ws, size_t ws_size,
                              hipStream_t stream) {
    const float* x    = (const float*)d_in[0];
    const float* w    = (const float*)d_in[1];
    const float* bias = (const float*)d_in[2];
    float* out = (float*)d_out;

    const size_t xt_bytes = (size_t)NB*HW*CIN*sizeof(__hip_bfloat16);
    const size_t wt_bytes = (size_t)OCH*KSZ*sizeof(__hip_bfloat16);

    if (ws_size >= xt_bytes + wt_bytes) {
        __hip_bfloat16* xt  = (__hip_bfloat16*)d_ws;
        __hip_bfloat16* wtp = (__hip_bfloat16*)((char*)d_ws + xt_bytes);
        hipLaunchKernelGGL(xpose_cast, dim3(HW/32, CIN/32, NB), dim3(32, 8), 0, stream, x, xt);
        hipLaunchKernelGGL(wcast, dim3((OCH*KSZ + 255)/256), dim3(256), 0, stream, w, wtp);
        hipLaunchKernelGGL(conv_mfma, dim3(NT), dim3(256), 0, stream, xt, wtp, bias, out);
    } else {
        size_t total = (size_t)NB*OCH*SPB;
        hipLaunchKernelGGL(conv_naive, dim3((unsigned)((total + 255)/256)), dim3(256), 0, stream,
                           x, w, bias, out);
    }
}